// Round 8
// baseline (243.225 us; speedup 1.0000x reference)
//
#include <hip/hip_runtime.h>
#include <math.h>

#define B_SZ 2048
#define R_SZ 64
#define TS 64                    // tile edge
#define NTILE (B_SZ / TS)        // 32
#define NBLK (NTILE + NTILE * (NTILE - 1) / 2)   // 32 diag + 496 pairs = 528

#define B_POW_NEG02 0.217637640824031f   // 2048^-0.2 = 2^-2.2
#define SQRT_2PI 2.5066282746310002f
#define LOG2E 1.44269504088896340736f

extern "C" __device__ float __ocml_native_exp2_f32(float);

typedef __attribute__((ext_vector_type(2))) float f32x2;

// ---------------------------------------------------------------------------
// ws layout (floats):
//   [0:64)    lscale        = 1/(B*h*sqrt(2pi))
//   [64:128)  cov_partial
//   [160]     ent_acc       (own line)
//   [192]     done2         (int, own line)
//   [256:256+131072)          U = kscale[r]*A   (prescaled, 512 KB)
//   [131328:...]              density (atomic-accumulated, 512 KB)
// ---------------------------------------------------------------------------

// Kernel 1: stats + Gram row + cov row + U prescale + density/flag zeroing.
__global__ __launch_bounds__(1024) void cov_stats_kernel(const float* __restrict__ A,
                                                         float* __restrict__ U,
                                                         float* __restrict__ density,
                                                         float* __restrict__ lscale,
                                                         float* __restrict__ cov_partial,
                                                         float* __restrict__ ent_acc,
                                                         int* __restrict__ done2) {
    int i = blockIdx.x;
    int tid = threadIdx.x;
    int j = tid & 63, bg = tid >> 6;          // 16 b-groups

    float g = 0.f, sj = 0.f, s2j = 0.f;
#pragma unroll 4
    for (int b = bg; b < B_SZ; b += 16) {
        float ai = A[b * R_SZ + i];           // wave-uniform broadcast
        float aj = A[b * R_SZ + j];           // coalesced
        g = fmaf(ai, aj, g);
        sj += aj;
        s2j = fmaf(aj, aj, s2j);
    }

    __shared__ float gred[16][64], sred[16][64], s2red[16][64];
    __shared__ float gfin[64], sfin[64], hs[64];
    gred[bg][j] = g; sred[bg][j] = sj; s2red[bg][j] = s2j;
    __syncthreads();
    if (tid < 64) {
        float G = 0.f, S = 0.f, S2 = 0.f;
#pragma unroll
        for (int t = 0; t < 16; ++t) { G += gred[t][j]; S += sred[t][j]; S2 += s2red[t][j]; }
        gfin[j] = G;
        sfin[j] = S;
        float m = S * (1.f / (float)B_SZ);
        float var = (S2 - S * m) * (1.f / (float)(B_SZ - 1));   // ddof=1
        var = fmaxf(var, 0.f);
        float h = fmaxf(1.06f * sqrtf(var) * B_POW_NEG02, 1e-4f);
        hs[j] = sqrtf(0.5f * LOG2E) / h;      // exp2(-(k*d)^2) = exp(-0.5(d/h)^2)
        if (i == 0) lscale[j] = 1.0f / ((float)B_SZ * h * SQRT_2PI);
    }
    __syncthreads();
    if (tid < 64) {                            // covariance row i
        float m_j = sfin[j] * (1.f / (float)B_SZ);
        float m_i = sfin[i] * (1.f / (float)B_SZ);
        float cov = (gfin[j] - (float)B_SZ * m_i * m_j) * (1.f / (float)(B_SZ - 1));
        float v = (j == i) ? 0.f : cov * cov;
        for (int off = 32; off > 0; off >>= 1) v += __shfl_down(v, off, 64);
        if (j == 0) cov_partial[i] = v;
    }
    if (i == 0 && tid == 64) { *ent_acc = 0.f; *done2 = 0; }

    // prescale U rows + zero density (64 blocks x 2048 elems each, exact)
    int base = i * (32 * R_SZ);
    float k0 = hs[tid & 63];
    U[base + tid]        = A[base + tid]        * k0;
    U[base + 1024 + tid] = A[base + 1024 + tid] * k0;
    density[base + tid] = 0.f;
    density[base + 1024 + tid] = 0.f;
}

// ---------------------------------------------------------------------------
// Kernel 2: symmetric KDE, 64x64 tile-pairs. 528 blocks x 1024 thr.
// Block: stage Ls (s-tile) once; wave w owns q rows {w, w+16, w+32, w+48}
// of the q-tile (registers) and sweeps ALL 64 s rows (staggered start), so
// row sums finish in-register. Column credit: one native ds_add_f32 per
// 4 exps into colbuf (LDS pipe — off the vmcnt FIFO). Flush via global
// native fadd atomics (8 per thread max). Diag tiles: rows only.
// ---------------------------------------------------------------------------
__global__ __launch_bounds__(1024) void kde_sym_kernel(const float* __restrict__ U,
                                                       float* __restrict__ density) {
    __shared__ float Ls[TS][R_SZ];       // 16 KB
    __shared__ float colbuf[TS][R_SZ];   // 16 KB

    int tid = threadIdx.x;
    int r = tid & 63, w = tid >> 6;

    // decode tile-pair: t<32 -> diag tile t; else upper-triangle (ti<tj)
    int t = blockIdx.x;
    int ti, tj;
    bool diag;
    if (t < NTILE) {
        ti = tj = t; diag = true;
    } else {
        int p = t - NTILE; diag = false;
        ti = 0;
        int cnt = NTILE - 1;
        while (p >= cnt) { p -= cnt; ti++; cnt--; }
        tj = ti + 1 + p;
    }
    int q0 = ti * TS, s0 = tj * TS;

    // stage s-tile (1 float4/thread) + zero colbuf
    {
        const float4* src = (const float4*)(U + s0 * R_SZ);
        float4* dst = (float4*)&Ls[0][0];
        dst[tid] = src[tid];
        float4* cb = (float4*)&colbuf[0][0];
        cb[tid] = make_float4(0.f, 0.f, 0.f, 0.f);
    }
    // q fragments (coalesced scalar loads, L2-hot)
    f32x2 uq01 = { U[(q0 + w +  0) * R_SZ + r], U[(q0 + w + 16) * R_SZ + r] };
    f32x2 uq23 = { U[(q0 + w + 32) * R_SZ + r], U[(q0 + w + 48) * R_SZ + r] };
    f32x2 r01 = {0.f, 0.f}, r23 = {0.f, 0.f};
    __syncthreads();

    int sbase = 4 * w;                    // stagger waves across colbuf rows
#pragma unroll 4
    for (int ii = 0; ii < TS; ++ii) {
        int s = sbase + ii; s &= (TS - 1);
        float us = Ls[s][r];
        f32x2 uss = { us, us };
        f32x2 d01 = uq01 - uss, d23 = uq23 - uss;
        f32x2 n01 = -d01 * d01, n23 = -d23 * d23;
        f32x2 e01 = { __ocml_native_exp2_f32(n01.x), __ocml_native_exp2_f32(n01.y) };
        f32x2 e23 = { __ocml_native_exp2_f32(n23.x), __ocml_native_exp2_f32(n23.y) };
        r01 += e01; r23 += e23;
        if (!diag) {                      // block-uniform branch
            f32x2 cs = e01 + e23;
            unsafeAtomicAdd(&colbuf[s][r], cs.x + cs.y);   // native ds_add_f32
        }
    }

    // row flush: wave w's 4 q-rows summed fully in-register
    unsafeAtomicAdd(&density[(q0 + w +  0) * R_SZ + r], r01.x);
    unsafeAtomicAdd(&density[(q0 + w + 16) * R_SZ + r], r01.y);
    unsafeAtomicAdd(&density[(q0 + w + 32) * R_SZ + r], r23.x);
    unsafeAtomicAdd(&density[(q0 + w + 48) * R_SZ + r], r23.y);

    if (!diag) {                          // column flush
        __syncthreads();
#pragma unroll
        for (int i = 0; i < 4; ++i) {
            int srow = w + 16 * i;
            unsafeAtomicAdd(&density[(s0 + srow) * R_SZ + r], colbuf[srow][r]);
        }
    }
}

// ---------------------------------------------------------------------------
// Kernel 3: entropy over assembled density + grid-final fold.
// 64 blocks x 1024; 2 elems/thread; last block folds cov+ent -> out[0].
// ---------------------------------------------------------------------------
__global__ __launch_bounds__(1024) void entropy_kernel(const float* __restrict__ density,
                                                       const float* __restrict__ lscale,
                                                       const float* __restrict__ cov_partial,
                                                       float* __restrict__ ent_acc,
                                                       int* __restrict__ done2,
                                                       float* __restrict__ out) {
    int tid = threadIdx.x;
    int r = tid & 63, sg = tid >> 6;
    float ls = lscale[r];
    int f = blockIdx.x * 2048 + tid;
    float v = __logf(fmaf(density[f], ls, 1e-8f))
            + __logf(fmaf(density[f + 1024], ls, 1e-8f));
    for (int off = 32; off > 0; off >>= 1) v += __shfl_down(v, off, 64);
    __shared__ float wr[16];
    if (r == 0) wr[sg] = v;
    __syncthreads();
    __shared__ int lastflag;
    if (tid == 0) {
        float s = 0.f;
#pragma unroll
        for (int ww = 0; ww < 16; ++ww) s += wr[ww];
        atomicAdd(ent_acc, s);             // once per block
        __threadfence();
        int prev = atomicAdd(done2, 1);
        lastflag = (prev == 63);
    }
    __syncthreads();
    if (lastflag && tid < 64) {            // grid-final fold in last block
        __threadfence();
        float v2 = cov_partial[tid];
        for (int off = 32; off > 0; off >>= 1) v2 += __shfl_down(v2, off, 64);
        if (tid == 0) {
            float ent = __hip_atomic_load(ent_acc, __ATOMIC_ACQUIRE,
                                          __HIP_MEMORY_SCOPE_AGENT);
            out[0] = ent * (1.0f / ((float)B_SZ * (float)R_SZ)) + v2;
        }
    }
}

extern "C" void kernel_launch(void* const* d_in, const int* in_sizes, int n_in,
                              void* d_out, int out_size, void* d_ws, size_t ws_size,
                              hipStream_t stream) {
    const float* A = (const float*)d_in[0];
    float* out = (float*)d_out;

    float* wsf = (float*)d_ws;
    float* lscale      = wsf;                 // 64
    float* cov_partial = wsf + 64;            // 64
    float* ent_acc     = wsf + 160;           // isolated line
    int*   done2       = (int*)(wsf + 192);
    float* U           = wsf + 256;           // 2048*64
    float* density     = wsf + 256 + B_SZ * R_SZ;

    cov_stats_kernel<<<R_SZ, 1024, 0, stream>>>(A, U, density, lscale, cov_partial,
                                                ent_acc, done2);
    kde_sym_kernel<<<NBLK, 1024, 0, stream>>>(U, density);
    entropy_kernel<<<64, 1024, 0, stream>>>(density, lscale, cov_partial,
                                            ent_acc, done2, out);
}

// Round 9
// 99.023 us; speedup vs baseline: 2.4563x; 2.4563x over previous
//
#include <hip/hip_runtime.h>
#include <math.h>

#define B_SZ 2048
#define R_SZ 64
#define QT 8                    // q rows per kde block
#define KDE_BLOCKS (B_SZ / QT)  // 256 blocks * 16 waves -> 1 block/CU

#define B_POW_NEG02 0.217637640824031f   // 2048^-0.2 = 2^-2.2
#define SQRT_2PI 2.5066282746310002f
#define LOG2E 1.44269504088896340736f

// native v_exp_f32 (exp2)
extern "C" __device__ float __ocml_native_exp2_f32(float);

typedef __attribute__((ext_vector_type(2))) float f32x2;  // -> v_pk_* f32 ops

// ---------------------------------------------------------------------------
// ws layout (floats):
//   [0:64)    lscale       = 1/(B*h*sqrt(2pi))
//   [64:128)  cov_partial  (one per receptor row)
//   [160]     ent_acc      (own 128B line)
//   [192]     done_cnt     (int, own line)
//   [256:256+131072)  U = kscale[r]*A  (prescaled input, 512 KB)
// ---------------------------------------------------------------------------

// Kernel 1: fused stats + Gram row + cov row + U prescale + flag init.
// (unchanged — verified correct since R4)
__global__ __launch_bounds__(1024) void cov_stats_kernel(const float* __restrict__ A,
                                                         float* __restrict__ U,
                                                         float* __restrict__ lscale,
                                                         float* __restrict__ cov_partial,
                                                         float* __restrict__ ent_acc,
                                                         int* __restrict__ done_cnt) {
    int i = blockIdx.x;
    int tid = threadIdx.x;
    int j = tid & 63, bg = tid >> 6;          // 16 b-groups

    float g = 0.f, sj = 0.f, s2j = 0.f;
#pragma unroll 4
    for (int b = bg; b < B_SZ; b += 16) {
        float ai = A[b * R_SZ + i];           // wave-uniform broadcast
        float aj = A[b * R_SZ + j];           // coalesced
        g = fmaf(ai, aj, g);
        sj += aj;
        s2j = fmaf(aj, aj, s2j);
    }

    __shared__ float gred[16][64], sred[16][64], s2red[16][64];
    __shared__ float gfin[64], sfin[64], hs[64];
    gred[bg][j] = g; sred[bg][j] = sj; s2red[bg][j] = s2j;
    __syncthreads();
    if (tid < 64) {
        float G = 0.f, S = 0.f, S2 = 0.f;
#pragma unroll
        for (int t = 0; t < 16; ++t) { G += gred[t][j]; S += sred[t][j]; S2 += s2red[t][j]; }
        gfin[j] = G;
        sfin[j] = S;
        float m = S * (1.f / (float)B_SZ);
        float var = (S2 - S * m) * (1.f / (float)(B_SZ - 1));   // ddof=1
        var = fmaxf(var, 0.f);
        float h = fmaxf(1.06f * sqrtf(var) * B_POW_NEG02, 1e-4f);
        hs[j] = sqrtf(0.5f * LOG2E) / h;      // exp2(-(k*d)^2) = exp(-0.5(d/h)^2)
        if (i == 0) lscale[j] = 1.0f / ((float)B_SZ * h * SQRT_2PI);
    }
    __syncthreads();
    if (tid < 64) {                            // covariance row i
        float m_j = sfin[j] * (1.f / (float)B_SZ);
        float m_i = sfin[i] * (1.f / (float)B_SZ);
        float cov = (gfin[j] - (float)B_SZ * m_i * m_j) * (1.f / (float)(B_SZ - 1));
        float v = (j == i) ? 0.f : cov * cov;
        for (int off = 32; off > 0; off >>= 1) v += __shfl_down(v, off, 64);
        if (j == 0) cov_partial[i] = v;
    }
    if (i == 0 && tid == 64) { *ent_acc = 0.f; *done_cnt = 0; }

    // prescale U rows [i*32, i*32+32): 2048 elems, 2 per thread (coalesced)
    int base = i * (32 * R_SZ);
    float k0 = hs[tid & 63];
    U[base + tid]        = A[base + tid]        * k0;
    U[base + 1024 + tid] = A[base + 1024 + tid] * k0;
}

// ---------------------------------------------------------------------------
// Kernel 2: pairwise KDE, QT=8, explicit 8-deep register prefetch pipeline.
// 256 blocks x 1024 thr (1 block/CU). Wave sg streams s = sg + 16k; the load
// for iteration k+8 issues before the compute of iteration k, so 8 loads are
// always in flight (oldest-only waits). No barriers/atomics in the loop.
// ---------------------------------------------------------------------------
__global__ __launch_bounds__(1024) void kde_kernel(const float* __restrict__ U,
                                                   const float* __restrict__ lscale,
                                                   const float* __restrict__ cov_partial,
                                                   float* __restrict__ ent_acc,
                                                   int* __restrict__ done_cnt,
                                                   float* __restrict__ out) {
    int tid = threadIdx.x;
    int r = tid & 63, sg = tid >> 6;
    int q0 = blockIdx.x * QT;

    f32x2 uq01 = { U[(q0 + 0) * R_SZ + r], U[(q0 + 1) * R_SZ + r] };
    f32x2 uq23 = { U[(q0 + 2) * R_SZ + r], U[(q0 + 3) * R_SZ + r] };
    f32x2 uq45 = { U[(q0 + 4) * R_SZ + r], U[(q0 + 5) * R_SZ + r] };
    f32x2 uq67 = { U[(q0 + 6) * R_SZ + r], U[(q0 + 7) * R_SZ + r] };
    f32x2 c01 = { 0.f, 0.f }, c23 = { 0.f, 0.f };
    f32x2 c45 = { 0.f, 0.f }, c67 = { 0.f, 0.f };

#define KDE_BODY(usv)                                                          \
    {                                                                          \
        f32x2 uss = { (usv), (usv) };                                          \
        f32x2 d01 = uq01 - uss, d23 = uq23 - uss;                              \
        f32x2 d45 = uq45 - uss, d67 = uq67 - uss;                              \
        f32x2 n01 = -d01 * d01, n23 = -d23 * d23;                              \
        f32x2 n45 = -d45 * d45, n67 = -d67 * d67;                              \
        f32x2 e01 = { __ocml_native_exp2_f32(n01.x), __ocml_native_exp2_f32(n01.y) }; \
        f32x2 e23 = { __ocml_native_exp2_f32(n23.x), __ocml_native_exp2_f32(n23.y) }; \
        f32x2 e45 = { __ocml_native_exp2_f32(n45.x), __ocml_native_exp2_f32(n45.y) }; \
        f32x2 e67 = { __ocml_native_exp2_f32(n67.x), __ocml_native_exp2_f32(n67.y) }; \
        c01 += e01; c23 += e23; c45 += e45; c67 += e67;                        \
    }

    // wave sg consumes s = sg + 16k, k = 0..127; element stride 16*64 = 1024
    const float* Up = U + sg * R_SZ + r;
    float p[8];
#pragma unroll
    for (int j = 0; j < 8; ++j) p[j] = Up[j * 1024];   // prologue: 8 in flight

    int li = 8 * 1024;
#pragma unroll 1
    for (int k = 0; k < 15; ++k) {                     // 15 x 8 = 120 consumed
#pragma unroll
        for (int j = 0; j < 8; ++j) {
            float us = p[j];
            p[j] = Up[li + j * 1024];                  // prefetch k+8 group
            KDE_BODY(us);
        }
        li += 8 * 1024;
    }
#pragma unroll
    for (int j = 0; j < 8; ++j) KDE_BODY(p[j]);        // drain last 8

#undef KDE_BODY

    // cross-wave reduction of the 8 query-row densities (32 KB LDS)
    __shared__ float red[16][QT][64];
    red[sg][0][r] = c01.x; red[sg][1][r] = c01.y;
    red[sg][2][r] = c23.x; red[sg][3][r] = c23.y;
    red[sg][4][r] = c45.x; red[sg][5][r] = c45.y;
    red[sg][6][r] = c67.x; red[sg][7][r] = c67.y;
    __syncthreads();
    __shared__ float wred[QT];
    if (sg < QT) {                             // wave sg owns query row sg
        float S = 0.f;
#pragma unroll
        for (int t = 0; t < 16; ++t) S += red[t][sg][r];
        float v = __logf(fmaf(S, lscale[r], 1e-8f));
        for (int off = 32; off > 0; off >>= 1) v += __shfl_down(v, off, 64);
        if (r == 0) wred[sg] = v;
    }
    __syncthreads();
    __shared__ int lastflag;
    if (tid == 0) {
        float p2 = 0.f;
#pragma unroll
        for (int t = 0; t < QT; ++t) p2 += wred[t];
        p2 *= (1.0f / ((float)B_SZ * (float)R_SZ));
        atomicAdd(ent_acc, p2);                // once per block
        __threadfence();
        int prev = atomicAdd(done_cnt, 1);
        lastflag = (prev == KDE_BLOCKS - 1);
    }
    __syncthreads();
    if (lastflag && tid < 64) {                // grid-final fold in last block
        __threadfence();
        float v = cov_partial[tid];
        for (int off = 32; off > 0; off >>= 1) v += __shfl_down(v, off, 64);
        if (tid == 0) {
            float ent = __hip_atomic_load(ent_acc, __ATOMIC_ACQUIRE,
                                          __HIP_MEMORY_SCOPE_AGENT);
            out[0] = ent + v;                  // COV_WEIGHT = 1.0
        }
    }
}

extern "C" void kernel_launch(void* const* d_in, const int* in_sizes, int n_in,
                              void* d_out, int out_size, void* d_ws, size_t ws_size,
                              hipStream_t stream) {
    const float* A = (const float*)d_in[0];
    float* out = (float*)d_out;

    float* wsf = (float*)d_ws;
    float* lscale      = wsf;            // 64
    float* cov_partial = wsf + 64;       // 64
    float* ent_acc     = wsf + 160;      // isolated cache line
    int*   done_cnt    = (int*)(wsf + 192);
    float* U           = wsf + 256;      // 2048*64 prescaled input

    cov_stats_kernel<<<R_SZ, 1024, 0, stream>>>(A, U, lscale, cov_partial,
                                                ent_acc, done_cnt);
    kde_kernel<<<KDE_BLOCKS, 1024, 0, stream>>>(U, lscale, cov_partial,
                                                ent_acc, done_cnt, out);
}